// Round 4
// baseline (386.015 us; speedup 1.0000x reference)
//
#include <hip/hip_runtime.h>
#include <hip/hip_bf16.h>

typedef short bf16x8 __attribute__((ext_vector_type(8)));
typedef float f32x4 __attribute__((ext_vector_type(4)));
typedef unsigned int u32x4 __attribute__((ext_vector_type(4)));

static __device__ __forceinline__ unsigned short f2bf(float f) {
  unsigned int u = __builtin_bit_cast(unsigned int, f);
  u += 0x7fffu + ((u >> 16) & 1u);
  return (unsigned short)(u >> 16);
}
static __device__ __forceinline__ float bf2f(unsigned short b) {
  unsigned int u = ((unsigned int)b) << 16;
  return __builtin_bit_cast(float, u);
}

// ---------------- proj: h = relu(x @ Wp.T + bp), x[8192,256], Wp[128,256] ----------------
__global__ void proj_kernel(const float* __restrict__ x, const float* __restrict__ Wp,
                            const float* __restrict__ bp, float* __restrict__ h) {
  __shared__ float xs[16][256];
  int r0 = blockIdx.x * 16;
  int j = threadIdx.x;  // 0..127
  for (int t = j; t < 16 * 256; t += 128)
    xs[t >> 8][t & 255] = x[(size_t)(r0 + (t >> 8)) * 256 + (t & 255)];
  __syncthreads();
  float acc[16];
#pragma unroll
  for (int r = 0; r < 16; ++r) acc[r] = 0.f;
  const float4* wp4 = reinterpret_cast<const float4*>(Wp + (size_t)j * 256);
#pragma unroll 4
  for (int k4 = 0; k4 < 64; ++k4) {
    float4 w = wp4[k4];
#pragma unroll
    for (int r = 0; r < 16; ++r) {
      float4 xv = *reinterpret_cast<const float4*>(&xs[r][k4 * 4]);
      acc[r] = fmaf(xv.x, w.x, acc[r]);
      acc[r] = fmaf(xv.y, w.y, acc[r]);
      acc[r] = fmaf(xv.z, w.z, acc[r]);
      acc[r] = fmaf(xv.w, w.w, acc[r]);
    }
  }
  float b = bp[j];
#pragma unroll
  for (int r = 0; r < 16; ++r) {
    float v = acc[r] + b;
    h[(size_t)(r0 + r) * 128 + j] = v > 0.f ? v : 0.f;
  }
}

// ---------- whs: Wh = hin @ W.T (K=128), write WhT bf16 [F][8192], s_src/s_dst f32 ----------
template <int F>
__global__ void whs_kernel(const float* __restrict__ hin, const float* __restrict__ W,
                           const float* __restrict__ a, unsigned short* __restrict__ WhT,
                           float* __restrict__ s_src, float* __restrict__ s_dst) {
  constexpr int NW = F / 64;
  __shared__ float hs[16][128];
  __shared__ float rs[2][16][NW];
  int r0 = blockIdx.x * 16;
  int j = threadIdx.x;  // 0..F-1
  for (int t = j; t < 16 * 128; t += F) hs[t >> 7][t & 127] = hin[(size_t)r0 * 128 + t];
  __syncthreads();
  float acc[16];
#pragma unroll
  for (int r = 0; r < 16; ++r) acc[r] = 0.f;
  const float4* w4 = reinterpret_cast<const float4*>(W + (size_t)j * 128);
#pragma unroll 4
  for (int k4 = 0; k4 < 32; ++k4) {
    float4 w = w4[k4];
#pragma unroll
    for (int r = 0; r < 16; ++r) {
      float4 xv = *reinterpret_cast<const float4*>(&hs[r][k4 * 4]);
      acc[r] = fmaf(xv.x, w.x, acc[r]);
      acc[r] = fmaf(xv.y, w.y, acc[r]);
      acc[r] = fmaf(xv.z, w.z, acc[r]);
      acc[r] = fmaf(xv.w, w.w, acc[r]);
    }
  }
  float asrc = a[j], adst = a[F + j];
  int lane = j & 63, wv = j >> 6;
#pragma unroll
  for (int r = 0; r < 16; ++r) {
    WhT[(size_t)j * 8192 + r0 + r] = f2bf(acc[r]);
    float vs = acc[r] * asrc, vd = acc[r] * adst;
#pragma unroll
    for (int off = 32; off; off >>= 1) {
      vs += __shfl_xor(vs, off);
      vd += __shfl_xor(vd, off);
    }
    if (lane == 0) { rs[0][r][wv] = vs; rs[1][r][wv] = vd; }
  }
  __syncthreads();
  if (j < 16) {
    float vs = 0.f, vd = 0.f;
    for (int w = 0; w < NW; ++w) { vs += rs[0][j][w]; vd += rs[1][j][w]; }
    s_src[r0 + j] = vs;
    s_dst[r0 + j] = vd;
  }
}

// -------- gmaxp: 32-block partial max of 8192 floats --------
__global__ void gmaxp_kernel(const float* __restrict__ v, float* __restrict__ pmax) {
  __shared__ float red[4];
  int lane = threadIdx.x & 63, wv = threadIdx.x >> 6;
  float mx = v[blockIdx.x * 256 + threadIdx.x];
#pragma unroll
  for (int off = 32; off; off >>= 1) mx = fmaxf(mx, __shfl_xor(mx, off));
  if (lane == 0) red[wv] = mx;
  __syncthreads();
  if (threadIdx.x == 0)
    pmax[blockIdx.x] = fmaxf(fmaxf(red[0], red[1]), fmaxf(red[2], red[3]));
}

// -------- bd: fold partial max -> g; emit per-col B=exp(sd-g), D=exp(.2(sd-g));
//          per-row A=exp(min(.8*e0,0)), C=exp(min(-.8*e0,0)), e0=s_src+g --------
__global__ void bd_kernel(const float* __restrict__ s_src, const float* __restrict__ s_dst,
                          const float* __restrict__ pmax, float* __restrict__ B,
                          float* __restrict__ D, float2* __restrict__ AC) {
  const float4* p4 = reinterpret_cast<const float4*>(pmax);
  float g = -1e30f;
#pragma unroll
  for (int q = 0; q < 8; ++q) {
    float4 p = p4[q];
    g = fmaxf(g, fmaxf(fmaxf(p.x, p.y), fmaxf(p.z, p.w)));
  }
  int j = blockIdx.x * 256 + threadIdx.x;
  float sd = s_dst[j] - g;
  B[j] = __expf(sd);
  D[j] = __expf(0.2f * sd);
  float e0 = s_src[j] + g;
  float A = __expf(fminf(0.8f * e0, 0.f));
  float C = __expf(fminf(-0.8f * e0, 0.f));
  AC[j] = make_float2(A, C);
}

// ---------------- fused flash-GAT pass ----------------
// p = max(A_i*B_j, C_i*D_j) masked — exact softmax weight exp(lrelu(e)-m), no exp in
// the loop. bf16 pack by truncation (v_perm); truncation bias cancels in the ratio
// because lsum (ones-MFMA) sums the SAME truncated weights. Row-sum via MFMA.
// Unroll-by-2, adj/mask prefetched 2 windows ahead. Partials stored bf16.
template <int F, bool ADJ, int MINW>
__global__ __launch_bounds__(256, MINW) void attn_kernel(
    const int* __restrict__ adj, unsigned char* __restrict__ maskb,
    const float2* __restrict__ AC, const float* __restrict__ B,
    const float* __restrict__ D, const unsigned short* __restrict__ WhT,
    unsigned short* __restrict__ pacc, float* __restrict__ pl, int cps) {
  int lane = threadIdx.x & 63;
  int wv = threadIdx.x >> 6;
  int r0 = blockIdx.x * 64 + wv * 16;
  int cbeg = blockIdx.y * cps;
  int cend = cbeg + cps;
  int rsub = lane & 15;
  int kg = lane >> 4;
  int row = r0 + rsub;
  float2 ac = AC[row];
  float A = ac.x, C = ac.y;
  f32x4 acc[F / 16];
#pragma unroll
  for (int t = 0; t < F / 16; ++t) acc[t] = (f32x4)0.f;
  f32x4 accl = (f32x4)0.f;
  bf16x8 ones;
#pragma unroll
  for (int jj = 0; jj < 8; ++jj) ones[jj] = (short)0x3F80;  // bf16 1.0

  const int4* ap = reinterpret_cast<const int4*>(adj + (size_t)row * 8192);
  unsigned char* mrow = maskb + (size_t)row * 1024;

#define GAT_BODY(CC, MB)                                                                   \
  {                                                                                        \
    float4 b0 = *reinterpret_cast<const float4*>(B + (CC));                                \
    float4 b1 = *reinterpret_cast<const float4*>(B + (CC) + 4);                            \
    float4 d0 = *reinterpret_cast<const float4*>(D + (CC));                                \
    float4 d1 = *reinterpret_cast<const float4*>(D + (CC) + 4);                            \
    float bv[8] = {b0.x, b0.y, b0.z, b0.w, b1.x, b1.y, b1.z, b1.w};                        \
    float dv[8] = {d0.x, d0.y, d0.z, d0.w, d1.x, d1.y, d1.z, d1.w};                        \
    u32x4 w;                                                                               \
    _Pragma("unroll") for (int q = 0; q < 4; ++q) {                                        \
      float plo = fmaxf(A * bv[2 * q], C * dv[2 * q]);                                     \
      float phi = fmaxf(A * bv[2 * q + 1], C * dv[2 * q + 1]);                             \
      plo = (((MB) >> (2 * q)) & 1u) ? plo : 0.f;                                          \
      phi = (((MB) >> (2 * q + 1)) & 1u) ? phi : 0.f;                                      \
      w[q] = __builtin_amdgcn_perm(__builtin_bit_cast(unsigned int, phi),                  \
                                   __builtin_bit_cast(unsigned int, plo), 0x07060302u);    \
    }                                                                                      \
    bf16x8 af = __builtin_bit_cast(bf16x8, w);                                             \
    accl = __builtin_amdgcn_mfma_f32_16x16x32_bf16(af, ones, accl, 0, 0, 0);               \
    _Pragma("unroll") for (int t = 0; t < F / 16; ++t) {                                   \
      bf16x8 bf = *reinterpret_cast<const bf16x8*>(WhT + (size_t)(t * 16 + rsub) * 8192 +  \
                                                   (CC));                                  \
      acc[t] = __builtin_amdgcn_mfma_f32_16x16x32_bf16(af, bf, acc[t], 0, 0, 0);           \
    }                                                                                      \
  }

  int c = cbeg + kg * 8;
  // pipeline prologue: stage X = window k0, stage Y = window k0+32
  int4 xa0, xa1, ya0, ya1;
  unsigned int xm = 0, ym = 0;
  if (ADJ) {
    xa0 = ap[c >> 2];
    xa1 = ap[(c >> 2) + 1];
    ya0 = ap[(c + 32) >> 2];
    ya1 = ap[((c + 32) >> 2) + 1];
  } else {
    xm = mrow[c >> 3];
    ym = mrow[(c + 32) >> 3];
  }

  for (int k0 = cbeg; k0 < cend; k0 += 64) {
    // ---- stage X (window k0, lane col c) ----
    {
      unsigned int mb;
      if (ADJ) {
        mb = (unsigned)((xa0.x > 0) | ((xa0.y > 0) << 1) | ((xa0.z > 0) << 2) |
                        ((xa0.w > 0) << 3) | ((xa1.x > 0) << 4) | ((xa1.y > 0) << 5) |
                        ((xa1.z > 0) << 6) | ((xa1.w > 0) << 7));
        int cn = (k0 + 64 < cend) ? c + 64 : c;  // prefetch 2 windows ahead (clamped)
        xa0 = ap[cn >> 2];
        xa1 = ap[(cn >> 2) + 1];
        mrow[c >> 3] = (unsigned char)mb;
      } else {
        mb = xm;
        int cn = (k0 + 64 < cend) ? c + 64 : c;
        xm = mrow[cn >> 3];
      }
      GAT_BODY(c, mb)
    }
    // ---- stage Y (window k0+32, lane col c+32) ----
    {
      unsigned int mb;
      if (ADJ) {
        mb = (unsigned)((ya0.x > 0) | ((ya0.y > 0) << 1) | ((ya0.z > 0) << 2) |
                        ((ya0.w > 0) << 3) | ((ya1.x > 0) << 4) | ((ya1.y > 0) << 5) |
                        ((ya1.z > 0) << 6) | ((ya1.w > 0) << 7));
        int cn = (k0 + 96 < cend) ? c + 96 : c;
        ya0 = ap[cn >> 2];
        ya1 = ap[(cn >> 2) + 1];
        mrow[(c + 32) >> 3] = (unsigned char)mb;
      } else {
        mb = ym;
        int cn = (k0 + 96 < cend) ? c + 96 : c;
        ym = mrow[cn >> 3];
      }
      GAT_BODY(c + 32, mb)
    }
    c += 64;
  }
#undef GAT_BODY

  // row-sums: accl D[row][col] with all cols equal; take col 0 (rsub==0) per kg group
  if (rsub == 0) {
#pragma unroll
    for (int q = 0; q < 4; ++q)
      pl[(size_t)blockIdx.y * 8192 + r0 + kg * 4 + q] = accl[q];
  }
#pragma unroll
  for (int t = 0; t < F / 16; ++t) {
    int col = t * 16 + rsub;
#pragma unroll
    for (int q = 0; q < 4; ++q) {
      int ro = r0 + kg * 4 + q;  // C/D mapping: col=lane&15, row=(lane>>4)*4+reg
      pacc[(size_t)blockIdx.y * 8192 * F + (size_t)ro * F + col] = f2bf(acc[t][q]);
    }
  }
}

// -------- epilogue: out = (sum_s pacc) / (sum_s l), optional ELU, runtime S --------
template <int F, bool ELU>
__global__ void epi_kernel(const unsigned short* __restrict__ pacc,
                           const float* __restrict__ pl, float* __restrict__ out, int S) {
  int idx = blockIdx.x * 256 + threadIdx.x;
  int row = idx / F;
  float l = 0.f, a = 0.f;
  for (int s = 0; s < S; ++s) {
    l += pl[(size_t)s * 8192 + row];
    a += bf2f(pacc[(size_t)s * 8192 * F + idx]);
  }
  float v = a / l;
  if (ELU) v = v > 0.f ? v : expm1f(v);
  out[idx] = v;
}

extern "C" void kernel_launch(void* const* d_in, const int* in_sizes, int n_in,
                              void* d_out, int out_size, void* d_ws, size_t ws_size,
                              hipStream_t stream) {
  const float* x  = (const float*)d_in[0];
  const int* adj  = (const int*)d_in[1];
  const float* Wp = (const float*)d_in[2];
  const float* bp = (const float*)d_in[3];
  const float* W1 = (const float*)d_in[4];
  const float* a1 = (const float*)d_in[5];
  const float* W2 = (const float*)d_in[6];
  const float* a2 = (const float*)d_in[7];
  float* out = (float*)d_out;

  // workspace: fixed 21 MiB + S*(2+1) MiB (bf16 partials)
  int S = 4;
  if (ws_size >= (21ull + 16 * 3) * 1024 * 1024) S = 16;
  else if (ws_size >= (21ull + 8 * 3) * 1024 * 1024) S = 8;
  int cps = 8192 / S;

  char* ws = (char*)d_ws;
  float* h             = (float*)(ws + 0);                      // 0-4 MiB
  unsigned short* WhT1 = (unsigned short*)(ws + (4ull << 20));  // 4-6
  unsigned short* WhT2 = (unsigned short*)(ws + (6ull << 20));  // 6-7
  char* sm = ws + (7ull << 20);                                 // 7-8 MiB small region
  float* s_src1 = (float*)(sm + 0 * 32768);
  float* s_dst1 = (float*)(sm + 1 * 32768);
  float* s_src2 = (float*)(sm + 2 * 32768);
  float* s_dst2 = (float*)(sm + 3 * 32768);
  float* B1     = (float*)(sm + 4 * 32768);
  float* D1     = (float*)(sm + 5 * 32768);
  float* B2     = (float*)(sm + 6 * 32768);
  float* D2     = (float*)(sm + 7 * 32768);
  float2* AC1   = (float2*)(sm + 8 * 32768);    // 64 KiB
  float2* AC2   = (float2*)(sm + 10 * 32768);   // 64 KiB
  float* pmax   = (float*)(sm + 12 * 32768);
  unsigned char* maskb = (unsigned char*)(ws + (8ull << 20));   // 8-16
  float* h1     = (float*)(ws + (16ull << 20));                 // 16-20
  float* pl1    = (float*)(ws + (20ull << 20));                 // 20-20.5
  float* pl2    = (float*)(ws + (20ull << 20) + (512u << 10));  // 20.5-21
  unsigned short* pacc1 = (unsigned short*)(ws + (21ull << 20));          // S*2 MiB
  unsigned short* pacc2 = pacc1 + (size_t)S * 8192 * 128;                 // S*1 MiB

  proj_kernel<<<512, 128, 0, stream>>>(x, Wp, bp, h);
  whs_kernel<128><<<512, 128, 0, stream>>>(h, W1, a1, WhT1, s_src1, s_dst1);
  gmaxp_kernel<<<32, 256, 0, stream>>>(s_dst1, pmax);
  bd_kernel<<<32, 256, 0, stream>>>(s_src1, s_dst1, pmax, B1, D1, AC1);
  attn_kernel<128, true, 4><<<dim3(128, S), 256, 0, stream>>>(
      adj, maskb, AC1, B1, D1, WhT1, pacc1, pl1, cps);
  epi_kernel<128, true><<<4096, 256, 0, stream>>>(pacc1, pl1, h1, S);
  whs_kernel<64><<<512, 64, 0, stream>>>(h1, W2, a2, WhT2, s_src2, s_dst2);
  gmaxp_kernel<<<32, 256, 0, stream>>>(s_dst2, pmax);
  bd_kernel<<<32, 256, 0, stream>>>(s_src2, s_dst2, pmax, B2, D2, AC2);
  attn_kernel<64, false, 6><<<dim3(128, S), 256, 0, stream>>>(
      adj, maskb, AC2, B2, D2, WhT2, pacc2, pl2, cps);
  epi_kernel<64, false><<<2048, 256, 0, stream>>>(pacc2, pl2, out, S);
}

// Round 5
// 309.135 us; speedup vs baseline: 1.2487x; 1.2487x over previous
//
#include <hip/hip_runtime.h>
#include <hip/hip_bf16.h>

typedef short bf16x8 __attribute__((ext_vector_type(8)));
typedef float f32x4 __attribute__((ext_vector_type(4)));
typedef unsigned int u32x4 __attribute__((ext_vector_type(4)));

static __device__ __forceinline__ unsigned short f2bf(float f) {
  unsigned int u = __builtin_bit_cast(unsigned int, f);
  u += 0x7fffu + ((u >> 16) & 1u);
  return (unsigned short)(u >> 16);
}
static __device__ __forceinline__ float bf2f(unsigned short b) {
  unsigned int u = ((unsigned int)b) << 16;
  return __builtin_bit_cast(float, u);
}

// ---------------- proj: h = relu(x @ Wp.T + bp), x[8192,256], Wp[128,256] ----------------
__global__ void proj_kernel(const float* __restrict__ x, const float* __restrict__ Wp,
                            const float* __restrict__ bp, float* __restrict__ h) {
  __shared__ float xs[16][256];
  int r0 = blockIdx.x * 16;
  int j = threadIdx.x;  // 0..127
  for (int t = j; t < 16 * 256; t += 128)
    xs[t >> 8][t & 255] = x[(size_t)(r0 + (t >> 8)) * 256 + (t & 255)];
  __syncthreads();
  float acc[16];
#pragma unroll
  for (int r = 0; r < 16; ++r) acc[r] = 0.f;
  const float4* wp4 = reinterpret_cast<const float4*>(Wp + (size_t)j * 256);
#pragma unroll 4
  for (int k4 = 0; k4 < 64; ++k4) {
    float4 w = wp4[k4];
#pragma unroll
    for (int r = 0; r < 16; ++r) {
      float4 xv = *reinterpret_cast<const float4*>(&xs[r][k4 * 4]);
      acc[r] = fmaf(xv.x, w.x, acc[r]);
      acc[r] = fmaf(xv.y, w.y, acc[r]);
      acc[r] = fmaf(xv.z, w.z, acc[r]);
      acc[r] = fmaf(xv.w, w.w, acc[r]);
    }
  }
  float b = bp[j];
#pragma unroll
  for (int r = 0; r < 16; ++r) {
    float v = acc[r] + b;
    h[(size_t)(r0 + r) * 128 + j] = v > 0.f ? v : 0.f;
  }
}

// ---- whs: Wh = hin @ W.T (K=128). WhT col-blocked bf16: [8192/32][F][32].
//      Also s_src/s_dst f32. ----
template <int F>
__global__ void whs_kernel(const float* __restrict__ hin, const float* __restrict__ W,
                           const float* __restrict__ a, unsigned short* __restrict__ WhT,
                           float* __restrict__ s_src, float* __restrict__ s_dst) {
  constexpr int NW = F / 64;
  __shared__ float hs[16][128];
  __shared__ float rs[2][16][NW];
  int r0 = blockIdx.x * 16;
  int j = threadIdx.x;  // 0..F-1
  for (int t = j; t < 16 * 128; t += F) hs[t >> 7][t & 127] = hin[(size_t)r0 * 128 + t];
  __syncthreads();
  float acc[16];
#pragma unroll
  for (int r = 0; r < 16; ++r) acc[r] = 0.f;
  const float4* w4 = reinterpret_cast<const float4*>(W + (size_t)j * 128);
#pragma unroll 4
  for (int k4 = 0; k4 < 32; ++k4) {
    float4 w = w4[k4];
#pragma unroll
    for (int r = 0; r < 16; ++r) {
      float4 xv = *reinterpret_cast<const float4*>(&hs[r][k4 * 4]);
      acc[r] = fmaf(xv.x, w.x, acc[r]);
      acc[r] = fmaf(xv.y, w.y, acc[r]);
      acc[r] = fmaf(xv.z, w.z, acc[r]);
      acc[r] = fmaf(xv.w, w.w, acc[r]);
    }
  }
  float asrc = a[j], adst = a[F + j];
  int lane = j & 63, wv = j >> 6;
#pragma unroll
  for (int r = 0; r < 16; ++r) {
    int rr = r0 + r;
    WhT[(size_t)(rr >> 5) * (F * 32) + (size_t)j * 32 + (rr & 31)] = f2bf(acc[r]);
    float vs = acc[r] * asrc, vd = acc[r] * adst;
#pragma unroll
    for (int off = 32; off; off >>= 1) {
      vs += __shfl_xor(vs, off);
      vd += __shfl_xor(vd, off);
    }
    if (lane == 0) { rs[0][r][wv] = vs; rs[1][r][wv] = vd; }
  }
  __syncthreads();
  if (j < 16) {
    float vs = 0.f, vd = 0.f;
    for (int w = 0; w < NW; ++w) { vs += rs[0][j][w]; vd += rs[1][j][w]; }
    s_src[r0 + j] = vs;
    s_dst[r0 + j] = vd;
  }
}

// -------- gmaxp: 32-block partial max of 8192 floats --------
__global__ void gmaxp_kernel(const float* __restrict__ v, float* __restrict__ pmax) {
  __shared__ float red[4];
  int lane = threadIdx.x & 63, wv = threadIdx.x >> 6;
  float mx = v[blockIdx.x * 256 + threadIdx.x];
#pragma unroll
  for (int off = 32; off; off >>= 1) mx = fmaxf(mx, __shfl_xor(mx, off));
  if (lane == 0) red[wv] = mx;
  __syncthreads();
  if (threadIdx.x == 0)
    pmax[blockIdx.x] = fmaxf(fmaxf(red[0], red[1]), fmaxf(red[2], red[3]));
}

// -------- bd: fold partial max -> g; emit per-col B=exp(sd-g), D=exp(.2(sd-g));
//          per-row A=exp(min(.8*e0,0)), C=exp(min(-.8*e0,0)), e0=s_src+g --------
__global__ void bd_kernel(const float* __restrict__ s_src, const float* __restrict__ s_dst,
                          const float* __restrict__ pmax, float* __restrict__ B,
                          float* __restrict__ D, float2* __restrict__ AC) {
  const float4* p4 = reinterpret_cast<const float4*>(pmax);
  float g = -1e30f;
#pragma unroll
  for (int q = 0; q < 8; ++q) {
    float4 p = p4[q];
    g = fmaxf(g, fmaxf(fmaxf(p.x, p.y), fmaxf(p.z, p.w)));
  }
  int j = blockIdx.x * 256 + threadIdx.x;
  float sd = s_dst[j] - g;
  B[j] = __expf(sd);
  D[j] = __expf(0.2f * sd);
  float e0 = s_src[j] + g;
  float A = __expf(fminf(0.8f * e0, 0.f));
  float C = __expf(fminf(-0.8f * e0, 0.f));
  AC[j] = make_float2(A, C);
}

// ---------------- fused flash-GAT pass ----------------
// p = max(A_i*B_j, C_i*D_j) masked = exact softmax weight exp(lrelu(e)-m).
// Register software-pipeline tuned for COUNTED vmcnt waits (never drain prefetch):
//   adj/mask staged 2 windows ahead (64-col ping-pong A/B),
//   B/D staged 1 window ahead (ping-pong 0/1),
//   WhT (L2-hot contiguous 8KB col-block tile) loaded at window top BEFORE the
//   next prefetch issues, so the MFMA's wait leaves the prefetches in flight.
// WhT layout: [c/32][F][32] bf16. Row-sums via ones-MFMA. Partials stored bf16.
template <int F, bool ADJ, int MINW>
__global__ __launch_bounds__(256, MINW) void attn_kernel(
    const int* __restrict__ adj, unsigned char* __restrict__ maskb,
    const float2* __restrict__ AC, const float* __restrict__ Bv,
    const float* __restrict__ Dv, const unsigned short* __restrict__ WhT,
    unsigned short* __restrict__ pacc, float* __restrict__ pl, int cps) {
  int lane = threadIdx.x & 63;
  int wv = threadIdx.x >> 6;
  int r0 = blockIdx.x * 64 + wv * 16;
  int cbeg = blockIdx.y * cps;
  int cend = cbeg + cps;
  int rsub = lane & 15;
  int kg = lane >> 4;
  int row = r0 + rsub;
  float2 ac = AC[row];
  float Af = ac.x, Cf = ac.y;
  f32x4 acc[F / 16];
#pragma unroll
  for (int t = 0; t < F / 16; ++t) acc[t] = (f32x4)0.f;
  f32x4 accl = (f32x4)0.f;
  bf16x8 ones;
#pragma unroll
  for (int jj = 0; jj < 8; ++jj) ones[jj] = (short)0x3F80;  // bf16 1.0

  const int4* ap = reinterpret_cast<const int4*>(adj + (size_t)row * 8192);
  unsigned char* mrow = maskb + (size_t)row * 1024;
  const int laneoff = rsub * 32 + kg * 8;

  // stage registers
  int4 a0A, a1A, a2A, a3A, a0B, a1B, a2B, a3B;
  unsigned int m0A = 0, m1A = 0, m0B = 0, m1B = 0;
  float4 b00, b10, d00, d10, b01, b11, d01, d11;
  bf16x8 w[F / 16];

#define WHT_LOAD(CC)                                                                      \
  {                                                                                       \
    const bf16x8* wp_ = reinterpret_cast<const bf16x8*>(                                  \
        WhT + (size_t)((CC) >> 5) * (F * 32) + laneoff);                                  \
    _Pragma("unroll") for (int t = 0; t < F / 16; ++t) w[t] = wp_[t * 64];                \
  }

#define BD_LOAD(S, CC)                                                                    \
  {                                                                                       \
    int cc_ = (CC) + kg * 8;                                                              \
    b0##S = *reinterpret_cast<const float4*>(Bv + cc_);                                   \
    b1##S = *reinterpret_cast<const float4*>(Bv + cc_ + 4);                               \
    d0##S = *reinterpret_cast<const float4*>(Dv + cc_);                                   \
    d1##S = *reinterpret_cast<const float4*>(Dv + cc_ + 4);                               \
  }

#define ADJ_LOAD(S, CC)                                                                   \
  {                                                                                       \
    int cc_ = (CC) + kg * 8;                                                              \
    if constexpr (ADJ) {                                                                  \
      a0##S = ap[cc_ >> 2];                                                               \
      a1##S = ap[(cc_ >> 2) + 1];                                                         \
      a2##S = ap[(cc_ >> 2) + 8];                                                         \
      a3##S = ap[(cc_ >> 2) + 9];                                                         \
    } else {                                                                              \
      m0##S = mrow[cc_ >> 3];                                                             \
      m1##S = mrow[(cc_ >> 3) + 4];                                                       \
    }                                                                                     \
  }

#define COMPUTEW(CC, AX, AY, MB_IN, PB0, PB1, PD0, PD1)                                   \
  {                                                                                       \
    unsigned int mb;                                                                      \
    if constexpr (ADJ) {                                                                  \
      mb = (unsigned)((AX.x > 0) | ((AX.y > 0) << 1) | ((AX.z > 0) << 2) |                \
                      ((AX.w > 0) << 3) | ((AY.x > 0) << 4) | ((AY.y > 0) << 5) |         \
                      ((AY.z > 0) << 6) | ((AY.w > 0) << 7));                             \
      mrow[((CC) + kg * 8) >> 3] = (unsigned char)mb;                                     \
    } else {                                                                              \
      mb = MB_IN;                                                                         \
    }                                                                                     \
    float bv_[8] = {PB0.x, PB0.y, PB0.z, PB0.w, PB1.x, PB1.y, PB1.z, PB1.w};              \
    float dv_[8] = {PD0.x, PD0.y, PD0.z, PD0.w, PD1.x, PD1.y, PD1.z, PD1.w};              \
    u32x4 pw_;                                                                            \
    _Pragma("unroll") for (int q = 0; q < 4; ++q) {                                       \
      float plo = fmaxf(Af * bv_[2 * q], Cf * dv_[2 * q]);                                \
      float phi = fmaxf(Af * bv_[2 * q + 1], Cf * dv_[2 * q + 1]);                        \
      plo = ((mb >> (2 * q)) & 1u) ? plo : 0.f;                                           \
      phi = ((mb >> (2 * q + 1)) & 1u) ? phi : 0.f;                                       \
      pw_[q] = __builtin_amdgcn_perm(__builtin_bit_cast(unsigned int, phi),               \
                                     __builtin_bit_cast(unsigned int, plo), 0x07060302u); \
    }                                                                                     \
    bf16x8 af = __builtin_bit_cast(bf16x8, pw_);                                          \
    accl = __builtin_amdgcn_mfma_f32_16x16x32_bf16(af, ones, accl, 0, 0, 0);              \
    _Pragma("unroll") for (int t = 0; t < F / 16; ++t) {                                  \
      acc[t] = __builtin_amdgcn_mfma_f32_16x16x32_bf16(af, w[t], acc[t], 0, 0, 0);        \
    }                                                                                     \
  }

  // HALF(P,Q,CC): compute windows CC, CC+32 from stage P; prefetch stage Q (CC+64..)
#define HALF(P, Q, CC)                                                                    \
  WHT_LOAD(CC)                                                                            \
  BD_LOAD(1, (CC) + 32)                                                                   \
  COMPUTEW(CC, a0##P, a1##P, m0##P, b00, b10, d00, d10)                                   \
  WHT_LOAD((CC) + 32)                                                                     \
  {                                                                                       \
    int na_ = ((CC) + 64 < cend) ? (CC) + 64 : cbeg;                                      \
    BD_LOAD(0, na_)                                                                       \
    ADJ_LOAD(Q, na_)                                                                      \
  }                                                                                       \
  COMPUTEW((CC) + 32, a2##P, a3##P, m1##P, b01, b11, d01, d11)

  // prologue: stage A = windows {0,1}, bd stage 0 = window 0
  ADJ_LOAD(A, cbeg)
  BD_LOAD(0, cbeg)

  for (int k0 = cbeg; k0 < cend; k0 += 128) {
    HALF(A, B, k0)
    HALF(B, A, k0 + 64)
  }
#undef HALF
#undef COMPUTEW
#undef ADJ_LOAD
#undef BD_LOAD
#undef WHT_LOAD

  // row-sums: accl D[row][col] with all cols equal; take col 0 (rsub==0) per kg group
  if (rsub == 0) {
#pragma unroll
    for (int q = 0; q < 4; ++q)
      pl[(size_t)blockIdx.y * 8192 + r0 + kg * 4 + q] = accl[q];
  }
#pragma unroll
  for (int t = 0; t < F / 16; ++t) {
    int col = t * 16 + rsub;
#pragma unroll
    for (int q = 0; q < 4; ++q) {
      int ro = r0 + kg * 4 + q;  // C/D mapping: col=lane&15, row=(lane>>4)*4+reg
      pacc[(size_t)blockIdx.y * 8192 * F + (size_t)ro * F + col] = f2bf(acc[t][q]);
    }
  }
}

// -------- epilogue: out = (sum_s pacc) / (sum_s l), optional ELU, runtime S --------
template <int F, bool ELU>
__global__ void epi_kernel(const unsigned short* __restrict__ pacc,
                           const float* __restrict__ pl, float* __restrict__ out, int S) {
  int idx = blockIdx.x * 256 + threadIdx.x;
  int row = idx / F;
  float l = 0.f, a = 0.f;
  for (int s = 0; s < S; ++s) {
    l += pl[(size_t)s * 8192 + row];
    a += bf2f(pacc[(size_t)s * 8192 * F + idx]);
  }
  float v = a / l;
  if (ELU) v = v > 0.f ? v : expm1f(v);
  out[idx] = v;
}

extern "C" void kernel_launch(void* const* d_in, const int* in_sizes, int n_in,
                              void* d_out, int out_size, void* d_ws, size_t ws_size,
                              hipStream_t stream) {
  const float* x  = (const float*)d_in[0];
  const int* adj  = (const int*)d_in[1];
  const float* Wp = (const float*)d_in[2];
  const float* bp = (const float*)d_in[3];
  const float* W1 = (const float*)d_in[4];
  const float* a1 = (const float*)d_in[5];
  const float* W2 = (const float*)d_in[6];
  const float* a2 = (const float*)d_in[7];
  float* out = (float*)d_out;

  // workspace: fixed 21 MiB + S*(2+1) MiB (bf16 partials)
  int S = 4;
  if (ws_size >= (21ull + 16 * 3) * 1024 * 1024) S = 16;
  else if (ws_size >= (21ull + 8 * 3) * 1024 * 1024) S = 8;
  int cps = 8192 / S;

  char* ws = (char*)d_ws;
  float* h             = (float*)(ws + 0);                      // 0-4 MiB
  unsigned short* WhT1 = (unsigned short*)(ws + (4ull << 20));  // 4-6
  unsigned short* WhT2 = (unsigned short*)(ws + (6ull << 20));  // 6-7
  char* sm = ws + (7ull << 20);                                 // 7-8 MiB small region
  float* s_src1 = (float*)(sm + 0 * 32768);
  float* s_dst1 = (float*)(sm + 1 * 32768);
  float* s_src2 = (float*)(sm + 2 * 32768);
  float* s_dst2 = (float*)(sm + 3 * 32768);
  float* B1     = (float*)(sm + 4 * 32768);
  float* D1     = (float*)(sm + 5 * 32768);
  float* B2     = (float*)(sm + 6 * 32768);
  float* D2     = (float*)(sm + 7 * 32768);
  float2* AC1   = (float2*)(sm + 8 * 32768);    // 64 KiB
  float2* AC2   = (float2*)(sm + 10 * 32768);   // 64 KiB
  float* pmax   = (float*)(sm + 12 * 32768);
  unsigned char* maskb = (unsigned char*)(ws + (8ull << 20));   // 8-16
  float* h1     = (float*)(ws + (16ull << 20));                 // 16-20
  float* pl1    = (float*)(ws + (20ull << 20));                 // 20-20.5
  float* pl2    = (float*)(ws + (20ull << 20) + (512u << 10));  // 20.5-21
  unsigned short* pacc1 = (unsigned short*)(ws + (21ull << 20));          // S*2 MiB
  unsigned short* pacc2 = pacc1 + (size_t)S * 8192 * 128;                 // S*1 MiB

  proj_kernel<<<512, 128, 0, stream>>>(x, Wp, bp, h);
  whs_kernel<128><<<512, 128, 0, stream>>>(h, W1, a1, WhT1, s_src1, s_dst1);
  gmaxp_kernel<<<32, 256, 0, stream>>>(s_dst1, pmax);
  bd_kernel<<<32, 256, 0, stream>>>(s_src1, s_dst1, pmax, B1, D1, AC1);
  attn_kernel<128, true, 3><<<dim3(128, S), 256, 0, stream>>>(
      adj, maskb, AC1, B1, D1, WhT1, pacc1, pl1, cps);
  epi_kernel<128, true><<<4096, 256, 0, stream>>>(pacc1, pl1, h1, S);
  whs_kernel<64><<<512, 64, 0, stream>>>(h1, W2, a2, WhT2, s_src2, s_dst2);
  gmaxp_kernel<<<32, 256, 0, stream>>>(s_dst2, pmax);
  bd_kernel<<<32, 256, 0, stream>>>(s_src2, s_dst2, pmax, B2, D2, AC2);
  attn_kernel<64, false, 4><<<dim3(128, S), 256, 0, stream>>>(
      adj, maskb, AC2, B2, D2, WhT2, pacc2, pl2, cps);
  epi_kernel<64, false><<<2048, 256, 0, stream>>>(pacc2, pl2, out, S);
}